// Round 4
// baseline (169.513 us; speedup 1.0000x reference)
//
#include <hip/hip_runtime.h>
#include <math.h>

#define Nq 2048
#define Bq 8
#define Kq 4
#define BKq 32
#define NL2 16  // elements per lane per wave (half row: 1024 / 64)
#define NP2 8   // float2 pairs per lane
#define TWO_PI_D 6.283185307179586
#define PI_D 3.141592653589793
#define INV2PI_D 0.15915494309189535

typedef float v2f __attribute__((ext_vector_type(2)));

__device__ __forceinline__ v2f mk2(float a, float b) {
  v2f r; r.x = a; r.y = b; return r;
}

#define ELEM(A, e) (((e) & 1) ? A[(e) >> 1].y : A[(e) >> 1].x)

// ---------------- wave helpers ----------------

__device__ __forceinline__ double wave_sum_d(double v) {
#pragma unroll
  for (int off = 1; off < 64; off <<= 1) v += __shfl_xor(v, off, 64);
  return v;
}

template <int CTRL, int RM, int BM>
__device__ __forceinline__ float dpp_add(float acc, float v) {
  return acc + __int_as_float(__builtin_amdgcn_update_dpp(
                   0, __float_as_int(v), CTRL, RM, BM, false));
}

// Canonical GCN DPP wave64 sum; result broadcast via lane 63.
__device__ __forceinline__ float dpp_sum_f32(float v) {
  v = dpp_add<0x111, 0xf, 0xf>(v, v);  // row_shr:1
  v = dpp_add<0x112, 0xf, 0xf>(v, v);  // row_shr:2
  v = dpp_add<0x114, 0xf, 0xe>(v, v);  // row_shr:4
  v = dpp_add<0x118, 0xf, 0xc>(v, v);  // row_shr:8
  v = dpp_add<0x142, 0xa, 0xf>(v, v);  // row_bcast:15
  v = dpp_add<0x143, 0xc, 0xf>(v, v);  // row_bcast:31
  return __int_as_float(__builtin_amdgcn_readlane(__float_as_int(v), 63));
}

// Two interleaved DPP sum trees (ILP overlap of the two latency chains).
__device__ __forceinline__ void dpp_sum2(float& v, float& w) {
  v = dpp_add<0x111, 0xf, 0xf>(v, v); w = dpp_add<0x111, 0xf, 0xf>(w, w);
  v = dpp_add<0x112, 0xf, 0xf>(v, v); w = dpp_add<0x112, 0xf, 0xf>(w, w);
  v = dpp_add<0x114, 0xf, 0xe>(v, v); w = dpp_add<0x114, 0xf, 0xe>(w, w);
  v = dpp_add<0x118, 0xf, 0xc>(v, v); w = dpp_add<0x118, 0xf, 0xc>(w, w);
  v = dpp_add<0x142, 0xa, 0xf>(v, v); w = dpp_add<0x142, 0xa, 0xf>(w, w);
  v = dpp_add<0x143, 0xc, 0xf>(v, v); w = dpp_add<0x143, 0xc, 0xf>(w, w);
  v = __int_as_float(__builtin_amdgcn_readlane(__float_as_int(v), 63));
  w = __int_as_float(__builtin_amdgcn_readlane(__float_as_int(w), 63));
}

// lane i <- lane i-1 via DPP wave_shr:1; lane0 -> 0 (zero ghost, relied upon)
__device__ __forceinline__ float dpp_shr1(float v) {
  return __int_as_float(__builtin_amdgcn_update_dpp(0, __float_as_int(v), 0x138, 0xf, 0xf, false));
}
// lane i <- lane i+1 via DPP wave_shl:1; lane63 -> 0
__device__ __forceinline__ float dpp_shl1(float v) {
  return __int_as_float(__builtin_amdgcn_update_dpp(0, __float_as_int(v), 0x130, 0xf, 0xf, false));
}

__device__ __forceinline__ double lane_excl_prefix_d(double T, int lane) {
  double acc = T;
#pragma unroll
  for (int off = 1; off < 64; off <<= 1) {
    double t = __shfl_up(acc, off, 64);
    if (lane >= off) acc += t;
  }
  return acc - T;
}

__device__ __forceinline__ void fast_sincos_ph(double ph, float* sn, float* cs) {
  double k = trunc(ph * INV2PI_D);
  float phr = (float)(ph - k * TWO_PI_D);
  __sincosf(phr, sn, cs);
}

// ---- half-row pentadiagonal apply: AP = coef*pent(V) + de.*V ----
// Wave covers 1024 contiguous elements. DPP gives intra-wave ghosts (zeros at
// wave edge lanes); the half-seam ghosts are patched from LDS; true-boundary
// rows get rank-small corrections. leftB: this wave holds rows 0..1023.
template <bool UD>
__device__ __forceinline__ void applyA_h(const v2f* V, v2f* AP, float coef,
                                         const v2f* De, float deu, int lane,
                                         bool leftB, const float* seam) {
  float lm2 = dpp_shr1(V[NP2 - 1].x);  // p[g-2]
  float lm1 = dpp_shr1(V[NP2 - 1].y);  // p[g-1]
  float rp1 = dpp_shl1(V[0].x);        // p[g+16]
  float rp2 = dpp_shl1(V[0].y);        // p[g+17]
  if (leftB) {
    if (lane == 63) { rp1 = seam[2]; rp2 = seam[3]; }  // p[1024], p[1025]
  } else {
    if (lane == 0) { lm2 = seam[0]; lm1 = seam[1]; }   // p[1022], p[1023]
  }
  v2f Vm = mk2(lm2, lm1), Vp = mk2(rp1, rp2);
#pragma unroll
  for (int j = 0; j < NP2; ++j) {
    v2f Vprev = (j == 0) ? Vm : V[j - 1];
    v2f Vnext = (j == NP2 - 1) ? Vp : V[j + 1];
    v2f t = Vprev + Vnext;         // m2 + q2 (pair-aligned)
    t += V[j] * 6.0f;
    float m1x = Vprev.y + V[j].y;  // p[2j-1] + p[2j+1]
    float m1y = V[j].x + Vnext.x;  // p[2j]   + p[2j+2]
    t.x -= 4.0f * m1x;
    t.y -= 4.0f * m1y;
    v2f de = UD ? mk2(deu, deu) : De[j];
    AP[j] = t * coef + de * V[j];
  }
  if (leftB && lane == 0) {  // true rows 0,1 vs zero-ghost interior formula
    AP[0].x += coef * (V[0].y - 4.0f * V[0].x);
    AP[0].y += coef * V[0].x;
  }
  if (!leftB && lane == 63) {  // true rows N-2, N-1
    AP[NP2 - 1].x += coef * V[NP2 - 1].y;
    AP[NP2 - 1].y += coef * (V[NP2 - 1].x - 4.0f * V[NP2 - 1].y);
  }
}

// ---- block CG: each system solved by a 2-wave pair (halves h=0/1). ----
// Single-reduction form: rsnew = a^2*(Ap.Ap) - rsold (exact by A-conjugacy),
// so one barrier pair per iteration. Early-break -> uniform freeze flag
// (identical across the pair) so barrier counts never diverge.
// Barrier discipline: seam/dot reads happen in section-1 (between barrier A
// and B); writes in section-2 (between B and next A).
template <bool UD, bool ZX>
__device__ __forceinline__ void cg_block(float coef, const v2f* De, float deu,
                                         v2f* R, v2f* X, int lane, bool leftB,
                                         float* seam, float* dot2, float* rs0s,
                                         int h) {
  v2f P[NP2], AP[NP2];
  if (!ZX) {
    // publish X0 seams
    if (leftB) {
      if (lane == 63) { seam[0] = X[NP2 - 1].x; seam[1] = X[NP2 - 1].y; }
    } else {
      if (lane == 0) { seam[2] = X[0].x; seam[3] = X[0].y; }
    }
    __syncthreads();
    applyA_h<UD>(X, AP, coef, De, deu, lane, leftB, seam);
#pragma unroll
    for (int j = 0; j < NP2; ++j) R[j] -= AP[j];
    __syncthreads();  // all waves done reading X seams before P seams written
  }
  float rs = 0.0f;
#pragma unroll
  for (int j = 0; j < NP2; ++j) {
    P[j] = R[j];
    rs += R[j].x * R[j].x + R[j].y * R[j].y;
  }
  rs = dpp_sum_f32(rs);
  if (lane == 0) rs0s[h] = rs;
  if (leftB) {
    if (lane == 63) { seam[0] = P[NP2 - 1].x; seam[1] = P[NP2 - 1].y; }
  } else {
    if (lane == 0) { seam[2] = P[0].x; seam[3] = P[0].y; }
  }
  __syncthreads();
  float rsold = rs0s[0] + rs0s[1];  // same order both halves -> identical
  float inv_rsold = __builtin_amdgcn_rcpf(rsold + 1e-12f);
  bool done = false;
  for (int it = 0; it < 30; ++it) {
    if (!done) {
      applyA_h<UD>(P, AP, coef, De, deu, lane, leftB, seam);
      float pp = 0.0f, aa = 0.0f;
#pragma unroll
      for (int j = 0; j < NP2; ++j) {
        pp += P[j].x * AP[j].x + P[j].y * AP[j].y;
        aa += AP[j].x * AP[j].x + AP[j].y * AP[j].y;
      }
      dpp_sum2(pp, aa);
      if (lane == 0) { dot2[h * 2 + 0] = pp; dot2[h * 2 + 1] = aa; }
    }
    __syncthreads();  // barrier B: partials published
    if (!done) {
      float pap = dot2[0] + dot2[2];
      float apap = dot2[1] + dot2[3];
      float a = rsold * __builtin_amdgcn_rcpf(pap + 1e-12f);
      float rsnew = a * (a * apap) - rsold;  // ordering avoids overflow
      if (rsnew < 1e-12f) {  // == sqrt(r.r) < 1e-6: final x,r update, freeze
#pragma unroll
        for (int j = 0; j < NP2; ++j) {
          X[j] += P[j] * a;
          R[j] -= AP[j] * a;
        }
        done = true;  // uniform across the pair (same pap/apap/rsold)
      } else {
        float bta = rsnew * inv_rsold;
#pragma unroll
        for (int j = 0; j < NP2; ++j) {
          X[j] += P[j] * a;
          R[j] -= AP[j] * a;
          P[j] = R[j] + P[j] * bta;
        }
        rsold = rsnew;
        inv_rsold = __builtin_amdgcn_rcpf(rsnew + 1e-12f);
        if (leftB) {
          if (lane == 63) { seam[0] = P[NP2 - 1].x; seam[1] = P[NP2 - 1].y; }
        } else {
          if (lane == 0) { seam[2] = P[0].x; seam[3] = P[0].y; }
        }
      }
    }
    __syncthreads();  // barrier A: seams ready for next applyA
  }
}

// ---- mega kernel: one block per (b,k) row; 4 waves: (sys X|Y) x (half 0|1) --
__global__ __launch_bounds__(256, 1) void row_kernel(
    const float* __restrict__ s, const float* __restrict__ eIF,
    const float* __restrict__ xm, const float* __restrict__ ym,
    const float* __restrict__ sum_x, const float* __restrict__ sum_y,
    const float* __restrict__ lamuda, const float* __restrict__ init_freqs,
    const int* __restrict__ mode_mask, const float* __restrict__ alpha_p,
    const float* __restrict__ beta_p, const float* __restrict__ var_p,
    const float* __restrict__ fs_p, const int* __restrict__ iter_p,
    const float* __restrict__ fe_w1, const float* __restrict__ fe_b1,
    const float* __restrict__ fe_w2, const float* __restrict__ fe_b2,
    const float* __restrict__ pr_w1, const float* __restrict__ pr_b1,
    const float* __restrict__ pr_w2, const float* __restrict__ pr_b2,
    const float* __restrict__ pr_w3, const float* __restrict__ pr_b3,
    const float* __restrict__ iter_w_p, double* __restrict__ hdr,
    float* __restrict__ out_eIF, float* __restrict__ out_xm,
    float* __restrict__ out_ym, float* __restrict__ cx_w,
    float* __restrict__ cy_w, float* __restrict__ out_scal) {
  __shared__ double sh_avg[Bq];
  __shared__ double sh_h1[Bq][32];
  __shared__ double sh_z[Bq][18];
  __shared__ double sh_z1[Bq][64];
  __shared__ double sh_z2[Bq][32];
  __shared__ double sh_res[Bq][2];
  __shared__ double sh_hdr[6];
  __shared__ double sh_nrm[2][2];   // [sys][h] f64 norm partials
  __shared__ double sh_ph[2][2];    // [sys][{left-half total, y0}] f64
  __shared__ float sh_seam[2][4];   // [sys][g1022,g1023,g1024,g1025]
  __shared__ float sh_dot[2][4];    // [sys][h*2 + {pap,apap}]
  __shared__ float sh_rs0[2][2];    // [sys][h]
  __shared__ float sh_xs[Nq], sh_ys[Nq];

  const int tid = threadIdx.x;
  const int wv = tid >> 6, lane = tid & 63;
  const int sys = wv >> 1, h = wv & 1;
  const bool leftB = (h == 0);
  const int row = blockIdx.x, b = row >> 2;
  const int bb = b * Nq, base = row * Nq;
  const int goff = h << 10;  // element offset of this wave's half

  // ---- hyperparameter MLP (redundant per block, f64 deterministic) ----
  double alpha = (double)alpha_p[0], beta = (double)beta_p[0];
  double iterv = (double)iter_p[0];
  if (tid < Bq) {
    double avg = 0.0;
#pragma unroll
    for (int k = 0; k < Kq; ++k) avg += (double)init_freqs[tid * Kq + k];
    sh_avg[tid] = avg * (1.0 / Kq);
  }
  __syncthreads();
  {  // 256 items == 256 threads
    int b2 = tid >> 5, j = tid & 31;
    double v = (double)fe_w1[j] * sh_avg[b2] + (double)fe_b1[j];
    sh_h1[b2][j] = v > 0.0 ? v : 0.0;
  }
  __syncthreads();
  if (tid < 128) {
    int b2 = tid >> 4, j = tid & 15;
    double acc = (double)fe_b2[j];
    for (int i = 0; i < 32; ++i) acc += (double)fe_w2[j * 32 + i] * sh_h1[b2][i];
    sh_z[b2][j] = acc > 0.0 ? acc : 0.0;
  }
  if (tid < Bq) {
    sh_z[tid][16] = alpha;
    sh_z[tid][17] = beta;
  }
  __syncthreads();
  for (int n = tid; n < 512; n += 256) {
    int b2 = n >> 6, j = n & 63;
    double acc = (double)pr_b1[j];
    for (int i = 0; i < 18; ++i) acc += (double)pr_w1[j * 18 + i] * sh_z[b2][i];
    sh_z1[b2][j] = acc > 0.0 ? acc : 0.0;
  }
  __syncthreads();
  {  // 256 items
    int b2 = tid >> 5, j = tid & 31;
    double acc = (double)pr_b2[j];
    for (int i = 0; i < 64; ++i) acc += (double)pr_w2[j * 64 + i] * sh_z1[b2][i];
    sh_z2[b2][j] = acc > 0.0 ? acc : 0.0;
  }
  __syncthreads();
  if (tid < 16) {
    int b2 = tid >> 1, c = tid & 1;
    double acc = (double)pr_b3[c];
    for (int i = 0; i < 32; ++i) acc += (double)pr_w3[c * 32 + i] * sh_z2[b2][i];
    double fac = 1.0 / (1.0 + exp(-(double)iter_w_p[0] * iterv));
    sh_res[b2][c] = tanh(acc) * fac * 0.1;
  }
  __syncthreads();
  if (tid == 0) {
    double r0 = 0.0, r1 = 0.0;
    for (int q = 0; q < Bq; ++q) { r0 += sh_res[q][0]; r1 += sh_res[q][1]; }
    double na = fmin(fmax(alpha + r0 * alpha * (1.0 / Bq), 1e-6), 0.01);
    double nb = fmin(fmax(beta + r1 * beta * (1.0 / Bq), 1e-6), 0.1);
    double betathr = fmin(pow(10.0, iterv / 36.0 - 10.0), nb);
    sh_hdr[0] = na;
    sh_hdr[1] = 2.0 / na;       // coefA
    sh_hdr[2] = 2.0 / betathr;  // coefS
    sh_hdr[3] = 1.0 / na;       // inv_alpha
    hdr[0] = na;
    hdr[4] = 1.0 / na;
    out_scal[0] = (float)na;
    out_scal[1] = (float)nb;
  }
  __syncthreads();
  const float coefA = (float)sh_hdr[1];
  const float coefS = (float)sh_hdr[2];
  const double inva = sh_hdr[3];
  const double fsv = (double)fs_p[0];
  const double c0 = PI_D / fsv;  // pi * dx

  // ---- u scale for batch b (each wave: its half; combine across halves) ----
  double tv[NL2];
  {
    const float4* S4 = reinterpret_cast<const float4*>(s + bb + goff);
    const float4* SX4 = reinterpret_cast<const float4*>(sum_x + bb + goff);
    const float4* SY4 = reinterpret_cast<const float4*>(sum_y + bb + goff);
    const float4* L4 = reinterpret_cast<const float4*>(lamuda + bb + goff);
    double n0 = 0.0, n1 = 0.0;
#pragma unroll
    for (int q = 0; q < 4; ++q) {
      float4 av = S4[lane * 4 + q];
      float4 bv = SX4[lane * 4 + q];
      float4 cv = SY4[lane * 4 + q];
      float4 dv = L4[lane * 4 + q];
      int e = 4 * q;
      tv[e + 0] = (double)av.x - (double)bv.x - (double)cv.x - (double)dv.x * inva;
      tv[e + 1] = (double)av.y - (double)bv.y - (double)cv.y - (double)dv.y * inva;
      tv[e + 2] = (double)av.z - (double)bv.z - (double)cv.z - (double)dv.z * inva;
      tv[e + 3] = (double)av.w - (double)bv.w - (double)cv.w - (double)dv.w * inva;
      n0 += tv[e + 0] * tv[e + 0];
      n1 += tv[e + 1] * tv[e + 1];
      n0 += tv[e + 2] * tv[e + 2];
      n1 += tv[e + 3] * tv[e + 3];
    }
    double part = wave_sum_d(n0 + n1);
    if (lane == 0) sh_nrm[sys][h] = part;
    __syncthreads();
    double nsq = sh_nrm[sys][0] + sh_nrm[sys][1];
    double nn = sqrt(nsq);
    double ee = sqrt((double)Nq * (double)var_p[0]);
    double scale = (nn > ee) ? ee / fmax(nn, 1e-30) : 1.0;
    if (tid == 0 && (row & 3) == 0) hdr[8 + b] = scale;  // for final_kernel
    double oms = 1.0 - scale;
#pragma unroll
    for (int e = 0; e < NL2; ++e) tv[e] *= oms;
  }

  // ---- eIF cumtrapz phase + trig + system build (half-row per wave) ----
  v2f De[NP2], R[NP2], X[NP2];
  {
    double ev[NL2], pl[NL2];
    const float4* E4 = reinterpret_cast<const float4*>(eIF + base + goff);
#pragma unroll
    for (int q = 0; q < 4; ++q) {
      float4 e4 = E4[lane * 4 + q];
      ev[4 * q + 0] = (double)e4.x;
      ev[4 * q + 1] = (double)e4.y;
      ev[4 * q + 2] = (double)e4.z;
      ev[4 * q + 3] = (double)e4.w;
    }
    pl[0] = ev[0];
#pragma unroll
    for (int e = 1; e < NL2; ++e) pl[e] = pl[e - 1] + ev[e];
    double offs = lane_excl_prefix_d(pl[NL2 - 1], lane);
    double tot = __shfl(offs + pl[NL2 - 1], 63, 64);
    if (lane == 0 && h == 0) {
      sh_ph[sys][0] = tot;     // sum of left half
      sh_ph[sys][1] = ev[0];   // global first element
    }
    __syncthreads();
    double pre = h ? sh_ph[sys][0] : 0.0;
    double y0 = sh_ph[sys][1];
    const float4* XM4 = reinterpret_cast<const float4*>(xm + base + goff);
    const float4* YM4 = reinterpret_cast<const float4*>(ym + base + goff);
#pragma unroll
    for (int q = 0; q < 4; ++q) {
      float4 xm4 = XM4[lane * 4 + q];
      float4 ym4 = YM4[lane * 4 + q];
      float xa[4] = {xm4.x, xm4.y, xm4.z, xm4.w};
      float ya[4] = {ym4.x, ym4.y, ym4.z, ym4.w};
#pragma unroll
      for (int t2 = 0; t2 < 4; ++t2) {
        int e = 4 * q + t2;
        double ph = c0 * (2.0 * (pre + offs + pl[e]) - ev[e] - y0);
        float sn, cs;
        fast_sincos_ph(ph, &sn, &cs);
        float xmv = xa[t2], ymv = ya[t2];
        double resid = tv[e] + (double)xmv * (double)cs + (double)ymv * (double)sn;
        float trig = (sys == 0) ? cs : sn;
        float de = trig * trig + 1e-6f;
        float rr = (float)((double)trig * resid);
        float xx = (sys == 0) ? xmv : ymv;
        int j = e >> 1;
        if (e & 1) {
          De[j].y = de; R[j].y = rr; X[j].y = xx;
        } else {
          De[j].x = de; R[j].x = rr; X[j].x = xx;
        }
      }
    }
  }

  // ---- first CG: sys0 pair solves X system, sys1 pair solves Y system ----
  cg_block<false, false>(coefA, De, 0.0f, R, X, lane, leftB, sh_seam[sys],
                         sh_dot[sys], sh_rs0[sys], h);

  // publish solutions (own half of own array)
  {
    float* dst = (sys == 0) ? sh_xs : sh_ys;
#pragma unroll
    for (int e = 0; e < NL2; ++e) dst[goff + lane * NL2 + e] = ELEM(X, e);
  }
  __syncthreads();

  // ---- deltaIF (each wave: its half; all values read from LDS) ----
  {
    float invdx = (float)fsv, inv2dx = 0.5f * invdx;
#pragma unroll
    for (int e = 0; e < NL2; ++e) {
      int i = goff + lane * NL2 + e;
      float xc = sh_xs[i], yc = sh_ys[i];
      float xb, yb;
      if (i == 0) {
        xb = (sh_xs[1] - xc) * invdx;
        yb = (sh_ys[1] - yc) * invdx;
      } else if (i == Nq - 1) {
        xb = (xc - sh_xs[Nq - 2]) * invdx;
        yb = (yc - sh_ys[Nq - 2]) * invdx;
      } else {
        xb = (sh_xs[i + 1] - sh_xs[i - 1]) * inv2dx;
        yb = (sh_ys[i + 1] - sh_ys[i - 1]) * inv2dx;
      }
      float denom = xc * xc + yc * yc + 1e-12f;
      float rr = (xc * yb - yc * xb) / (denom * (float)TWO_PI_D);
      int j = e >> 1;
      if (e & 1) {
        R[j].y = rr; X[j].y = 0.0f;
      } else {
        R[j].x = rr; X[j].x = 0.0f;
      }
    }
  }

  // ---- smooth CG (both sys pairs solve the identical system -> identical) --
  cg_block<true, true>(coefS, nullptr, 1.0f + 1e-6f, R, X, lane, leftB,
                       sh_seam[sys], sh_dot[sys], sh_rs0[sys], h);

  // ---- epilogue: outputs + new-phase contributions (half-row per wave) ----
  bool active = mode_mask[row] != 0;
  double eifn[NL2], pl2[NL2];
  {
    const float4* E4 = reinterpret_cast<const float4*>(eIF + base + goff);
#pragma unroll
    for (int q = 0; q < 4; ++q) {
      float4 e4 = E4[lane * 4 + q];
      double ea[4] = {(double)e4.x, (double)e4.y, (double)e4.z, (double)e4.w};
#pragma unroll
      for (int t2 = 0; t2 < 4; ++t2) {
        int e = 4 * q + t2;
        double sm = (double)ELEM(X, e);
        eifn[e] = active ? (ea[t2] - 0.5 * sm) : ea[t2];
      }
    }
  }
  if (sys == 0) {
#pragma unroll
    for (int e = 0; e < NL2; ++e) {
      int loc = goff + lane * NL2 + e;
      int i = base + loc;
      out_eIF[i] = (float)eifn[e];
      out_xm[i] = active ? sh_xs[loc] : xm[i];
    }
  } else {
#pragma unroll
    for (int e = 0; e < NL2; ++e) {
      int loc = goff + lane * NL2 + e;
      int i = base + loc;
      out_ym[i] = active ? sh_ys[loc] : ym[i];
    }
  }
  pl2[0] = eifn[0];
#pragma unroll
  for (int e = 1; e < NL2; ++e) pl2[e] = pl2[e - 1] + eifn[e];
  double offs2 = lane_excl_prefix_d(pl2[NL2 - 1], lane);
  double tot2 = __shfl(offs2 + pl2[NL2 - 1], 63, 64);
  __syncthreads();  // sh_ph reuse: all prior reads complete before overwrite
  if (lane == 0 && h == 0) {
    sh_ph[sys][0] = tot2;
    sh_ph[sys][1] = eifn[0];
  }
  __syncthreads();
  {
    double pre2 = h ? sh_ph[sys][0] : 0.0;
    double y02 = sh_ph[sys][1];
#pragma unroll
    for (int e = 0; e < NL2; ++e) {
      int loc = goff + lane * NL2 + e;
      int i = base + loc;
      double ph = c0 * (2.0 * (pre2 + offs2 + pl2[e]) - eifn[e] - y02);
      float sn, cs;
      fast_sincos_ph(ph, &sn, &cs);
      if (sys == 0)
        cx_w[i] = active ? sh_xs[loc] * cs : 0.0f;
      else
        cy_w[i] = active ? sh_ys[loc] * sn : 0.0f;
    }
  }
}

// ------- final: pure elementwise (scale precomputed by row_kernel) ----------
__global__ __launch_bounds__(128) void final_kernel(
    const float* __restrict__ s, const float* __restrict__ sum_x,
    const float* __restrict__ sum_y, const float* __restrict__ lamuda,
    const double* __restrict__ hdr, const float* __restrict__ cx_w,
    const float* __restrict__ cy_w, float* __restrict__ out_bsx,
    float* __restrict__ out_bsy, float* __restrict__ out_lam) {
  int gi = blockIdx.x * 128 + threadIdx.x;  // 128 blocks x 128 thr = 16384
  int b = gi >> 11, i = gi & (Nq - 1);
  double na = hdr[0], inva = hdr[4], scale = hdr[8 + b];
  double sv = (double)s[gi];
  double t = sv - (double)sum_x[gi] - (double)sum_y[gi] -
             (double)lamuda[gi] * inva;
  double bx = 0.0, by = 0.0;
#pragma unroll
  for (int k = 0; k < Kq; ++k) {
    bx += (double)cx_w[(b * Kq + k) * Nq + i];
    by += (double)cy_w[(b * Kq + k) * Nq + i];
  }
  double u = t * scale;
  double nl = (double)lamuda[gi] + na * (u + bx + by - sv);
  out_bsx[gi] = (float)bx;
  out_bsy[gi] = (float)by;
  out_lam[gi] = (float)nl;
}

// ---------------- launcher ----------------
extern "C" void kernel_launch(void* const* d_in, const int* in_sizes, int n_in,
                              void* d_out, int out_size, void* d_ws, size_t ws_size,
                              hipStream_t stream) {
  (void)in_sizes; (void)n_in; (void)out_size; (void)ws_size;
  const float* s = (const float*)d_in[0];
  const float* eIF = (const float*)d_in[1];
  const float* xm = (const float*)d_in[2];
  const float* ym = (const float*)d_in[3];
  const float* sum_x = (const float*)d_in[4];
  const float* sum_y = (const float*)d_in[5];
  const float* lamuda = (const float*)d_in[6];
  const float* init_freqs = (const float*)d_in[7];
  const int* mode_mask = (const int*)d_in[8];
  const float* alpha = (const float*)d_in[9];
  const float* beta = (const float*)d_in[10];
  const float* var = (const float*)d_in[11];
  const float* fs = (const float*)d_in[12];
  const int* iteration = (const int*)d_in[13];
  const float* fe_w1 = (const float*)d_in[14];
  const float* fe_b1 = (const float*)d_in[15];
  const float* fe_w2 = (const float*)d_in[16];
  const float* fe_b2 = (const float*)d_in[17];
  const float* pr_w1 = (const float*)d_in[18];
  const float* pr_b1 = (const float*)d_in[19];
  const float* pr_w2 = (const float*)d_in[20];
  const float* pr_b2 = (const float*)d_in[21];
  const float* pr_w3 = (const float*)d_in[22];
  const float* pr_b3 = (const float*)d_in[23];
  const float* iter_weight = (const float*)d_in[24];

  float* out = (float*)d_out;
  const int BN = Bq * Nq;      // 16384
  const int BKN = BKq * Nq;    // 65536
  float* out_eIF = out;
  float* out_xm = out + BKN;
  float* out_ym = out + 2 * BKN;
  float* out_bsx = out + 3 * BKN;
  float* out_bsy = out + 3 * BKN + BN;
  float* out_lam = out + 3 * BKN + 2 * BN;
  float* out_scal = out + 3 * BKN + 3 * BN;  // [new_alpha, new_beta]

  double* W = (double*)d_ws;
  double* hdr = W;                   // 16 doubles: [0]=na [4]=inva [8..15]=scale_b
  float* F = (float*)(W + 16);
  float* cx_w = F;                   // BKN floats
  float* cy_w = F + BKN;             // BKN floats

  row_kernel<<<BKq, 256, 0, stream>>>(
      s, eIF, xm, ym, sum_x, sum_y, lamuda, init_freqs, mode_mask, alpha, beta,
      var, fs, iteration, fe_w1, fe_b1, fe_w2, fe_b2, pr_w1, pr_b1, pr_w2,
      pr_b2, pr_w3, pr_b3, iter_weight, hdr, out_eIF, out_xm, out_ym, cx_w,
      cy_w, out_scal);
  final_kernel<<<BN / 128, 128, 0, stream>>>(s, sum_x, sum_y, lamuda, hdr,
                                             cx_w, cy_w, out_bsx, out_bsy,
                                             out_lam);
}

// Round 5
// 165.765 us; speedup vs baseline: 1.0226x; 1.0226x over previous
//
#include <hip/hip_runtime.h>
#include <math.h>

#define Nq 2048
#define Bq 8
#define Kq 4
#define BKq 32
#define NL 32  // elements per lane (2048 / 64)
#define NP 16  // float2 pairs per lane
#define TWO_PI_D 6.283185307179586
#define PI_D 3.141592653589793
#define INV2PI_D 0.15915494309189535

typedef float v2f __attribute__((ext_vector_type(2)));

__device__ __forceinline__ v2f mk2(float a, float b) {
  v2f r; r.x = a; r.y = b; return r;
}

// ---------------- wave helpers ----------------

__device__ __forceinline__ double wave_sum_d(double v) {
#pragma unroll
  for (int off = 1; off < 64; off <<= 1) v += __shfl_xor(v, off, 64);
  return v;
}

template <int CTRL, int RM, int BM>
__device__ __forceinline__ float dpp_add(float acc, float v) {
  return acc + __int_as_float(__builtin_amdgcn_update_dpp(
                   0, __float_as_int(v), CTRL, RM, BM, false));
}

// Canonical GCN DPP wave64 sum; result broadcast via lane 63.
__device__ __forceinline__ float dpp_sum_f32(float v) {
  v = dpp_add<0x111, 0xf, 0xf>(v, v);  // row_shr:1
  v = dpp_add<0x112, 0xf, 0xf>(v, v);  // row_shr:2
  v = dpp_add<0x114, 0xf, 0xe>(v, v);  // row_shr:4
  v = dpp_add<0x118, 0xf, 0xc>(v, v);  // row_shr:8
  v = dpp_add<0x142, 0xa, 0xf>(v, v);  // row_bcast:15
  v = dpp_add<0x143, 0xc, 0xf>(v, v);  // row_bcast:31
  return __int_as_float(__builtin_amdgcn_readlane(__float_as_int(v), 63));
}

// Two interleaved DPP sum trees (ILP overlap of the two latency chains).
__device__ __forceinline__ void dpp_sum2(float& v, float& w) {
  v = dpp_add<0x111, 0xf, 0xf>(v, v); w = dpp_add<0x111, 0xf, 0xf>(w, w);
  v = dpp_add<0x112, 0xf, 0xf>(v, v); w = dpp_add<0x112, 0xf, 0xf>(w, w);
  v = dpp_add<0x114, 0xf, 0xe>(v, v); w = dpp_add<0x114, 0xf, 0xe>(w, w);
  v = dpp_add<0x118, 0xf, 0xc>(v, v); w = dpp_add<0x118, 0xf, 0xc>(w, w);
  v = dpp_add<0x142, 0xa, 0xf>(v, v); w = dpp_add<0x142, 0xa, 0xf>(w, w);
  v = dpp_add<0x143, 0xc, 0xf>(v, v); w = dpp_add<0x143, 0xc, 0xf>(w, w);
  v = __int_as_float(__builtin_amdgcn_readlane(__float_as_int(v), 63));
  w = __int_as_float(__builtin_amdgcn_readlane(__float_as_int(w), 63));
}

// lane i <- lane i-1 via DPP wave_shr:1; lane0 -> 0 (zero ghost, relied upon)
__device__ __forceinline__ float dpp_shr1(float v) {
  return __int_as_float(__builtin_amdgcn_update_dpp(0, __float_as_int(v), 0x138, 0xf, 0xf, false));
}
// lane i <- lane i+1 via DPP wave_shl:1; lane63 -> 0
__device__ __forceinline__ float dpp_shl1(float v) {
  return __int_as_float(__builtin_amdgcn_update_dpp(0, __float_as_int(v), 0x130, 0xf, 0xf, false));
}

__device__ __forceinline__ double lane_excl_prefix_d(double T, int lane) {
  double acc = T;
#pragma unroll
  for (int off = 1; off < 64; off <<= 1) {
    double t = __shfl_up(acc, off, 64);
    if (lane >= off) acc += t;
  }
  return acc - T;
}

__device__ __forceinline__ void fast_sincos_ph(double ph, float* sn, float* cs) {
  double k = trunc(ph * INV2PI_D);
  float phr = (float)(ph - k * TWO_PI_D);
  __sincosf(phr, sn, cs);
}

// ---- packed CG: (coef*opedoub + diag(de)) z = rhs on one wave, f32 state ----
// Single-reduction form: one interleaved DPP tree-pair per iteration
// (pap & apap), rsnew = a^2*apap - rsold (exact by A-conjugacy), and a fully
// fused X/R/P update (bta known before the pass). Zero barriers, zero LDS.
// In: X = x0, R = rhs. Out: X = solution. ZERO_X0 skips the initial matvec.
template <bool UNIT_DIAG, bool ZERO_X0>
__device__ __forceinline__ void cg_wave_pk(float coef, const v2f* De, float deu,
                                           v2f* R, v2f* X, int lane) {
  v2f P[NP], AP[NP];

  // AP = coef * pent(V) + de .* V   (two-step: preserves exact stencil
  // cancellation for near-constant V — critical when coef ~ 1e10).
  // Interior formula everywhere (DPP zero-ghosts at wave edges), then
  // rank-small boundary corrections at lanes 0 / 63.
  auto applyA = [&](const v2f* V) {
    float lm2 = dpp_shr1(V[NP - 1].x);  // p[-2] (0 at lane 0)
    float lm1 = dpp_shr1(V[NP - 1].y);  // p[-1]
    float rp1 = dpp_shl1(V[0].x);       // p[32] (0 at lane 63)
    float rp2 = dpp_shl1(V[0].y);       // p[33]
    v2f Vm = mk2(lm2, lm1);
    v2f Vp = mk2(rp1, rp2);
#pragma unroll
    for (int j = 0; j < NP; ++j) {
      v2f Vprev = (j == 0) ? Vm : V[j - 1];
      v2f Vnext = (j == NP - 1) ? Vp : V[j + 1];
      v2f t = Vprev + Vnext;       // m2 + q2 (pair-aligned)
      t += V[j] * 6.0f;            // + 6 p
      float m1x = Vprev.y + V[j].y;  // p[2j-1] + p[2j+1]
      float m1y = V[j].x + Vnext.x;  // p[2j]   + p[2j+2]
      t.x -= 4.0f * m1x;
      t.y -= 4.0f * m1y;
      v2f de = UNIT_DIAG ? mk2(deu, deu) : De[j];
      AP[j] = t * coef + de * V[j];
    }
    // Boundary corrections: interior-with-zero-ghosts vs true boundary rows.
    if (lane == 0) {
      AP[0].x += coef * (V[0].y - 4.0f * V[0].x);   // row 0: 2p0-3p1+p2
      AP[0].y += coef * V[0].x;                     // row 1: -3p0+6p1-4p2+p3
    }
    if (lane == 63) {
      AP[NP - 1].x += coef * V[NP - 1].y;                      // row N-2
      AP[NP - 1].y += coef * (V[NP - 1].x - 4.0f * V[NP - 1].y);  // row N-1
    }
  };

  float rsold, inv_rsold;
  {
    if (!ZERO_X0) {
      applyA(X);
#pragma unroll
      for (int j = 0; j < NP; ++j) R[j] -= AP[j];
    }
    v2f a0 = mk2(0.f, 0.f), a1 = mk2(0.f, 0.f);
#pragma unroll
    for (int j = 0; j < NP; j += 2) {
      P[j] = R[j];
      a0 += R[j] * R[j];
      P[j + 1] = R[j + 1];
      a1 += R[j + 1] * R[j + 1];
    }
    v2f s = a0 + a1;
    rsold = dpp_sum_f32(s.x + s.y);
    inv_rsold = __builtin_amdgcn_rcpf(rsold + 1e-12f);  // hidden behind applyA
  }

  for (int it = 0; it < 30; ++it) {
    applyA(P);
    // pap (p.Ap) and apap (Ap.Ap) accumulated in interleaved short chains
    v2f p0 = mk2(0.f, 0.f), p1 = mk2(0.f, 0.f);
    v2f q0 = mk2(0.f, 0.f), q1 = mk2(0.f, 0.f);
#pragma unroll
    for (int j = 0; j < NP; j += 2) {
      p0 += P[j] * AP[j];
      q0 += AP[j] * AP[j];
      p1 += P[j + 1] * AP[j + 1];
      q1 += AP[j + 1] * AP[j + 1];
    }
    v2f ps = p0 + p1, qs = q0 + q1;
    float pap = ps.x + ps.y, apap = qs.x + qs.y;
    dpp_sum2(pap, apap);
    float a = rsold * __builtin_amdgcn_rcpf(pap + 1e-12f);
    float rsnew = a * (a * apap) - rsold;  // == |r - a*Ap|^2 (A-conjugacy)
    if (rsnew < 1e-12f) {  // == sqrt(r.r) < 1e-6: final x,r update, freeze
#pragma unroll
      for (int j = 0; j < NP; ++j) {
        X[j] += P[j] * a;
        R[j] -= AP[j] * a;
      }
      break;
    }
    float bta = rsnew * inv_rsold;  // rcp computed one iteration earlier
    // Fused X/R/P update. Boundary pairs (0, NP-1) first so the next
    // iteration's DPP shifts / boundary corrections can start early.
    {
      X[0] += P[0] * a;
      R[0] -= AP[0] * a;
      P[0] = R[0] + P[0] * bta;
      X[NP - 1] += P[NP - 1] * a;
      R[NP - 1] -= AP[NP - 1] * a;
      P[NP - 1] = R[NP - 1] + P[NP - 1] * bta;
    }
#pragma unroll
    for (int j = 1; j < NP - 1; ++j) {
      X[j] += P[j] * a;
      R[j] -= AP[j] * a;
      P[j] = R[j] + P[j] * bta;
    }
    rsold = rsnew;
    inv_rsold = __builtin_amdgcn_rcpf(rsnew + 1e-12f);  // hidden behind applyA
  }
}

// ---------- mega kernel: one block per (b,k) row; wave0=X system, wave1=Y ----
__global__ __launch_bounds__(128, 1) void row_kernel(
    const float* __restrict__ s, const float* __restrict__ eIF,
    const float* __restrict__ xm, const float* __restrict__ ym,
    const float* __restrict__ sum_x, const float* __restrict__ sum_y,
    const float* __restrict__ lamuda, const float* __restrict__ init_freqs,
    const int* __restrict__ mode_mask, const float* __restrict__ alpha_p,
    const float* __restrict__ beta_p, const float* __restrict__ var_p,
    const float* __restrict__ fs_p, const int* __restrict__ iter_p,
    const float* __restrict__ fe_w1, const float* __restrict__ fe_b1,
    const float* __restrict__ fe_w2, const float* __restrict__ fe_b2,
    const float* __restrict__ pr_w1, const float* __restrict__ pr_b1,
    const float* __restrict__ pr_w2, const float* __restrict__ pr_b2,
    const float* __restrict__ pr_w3, const float* __restrict__ pr_b3,
    const float* __restrict__ iter_w_p, double* __restrict__ hdr,
    float* __restrict__ out_eIF, float* __restrict__ out_xm,
    float* __restrict__ out_ym, float* __restrict__ cx_w,
    float* __restrict__ cy_w, float* __restrict__ out_scal) {
  __shared__ double sh_avg[Bq];
  __shared__ double sh_h1[Bq][32];
  __shared__ double sh_z[Bq][18];
  __shared__ double sh_z1[Bq][64];
  __shared__ double sh_z2[Bq][32];
  __shared__ double sh_res[Bq][2];
  __shared__ double sh_hdr[6];
  __shared__ float sh_xs[Nq], sh_ys[Nq];

  const int tid = threadIdx.x;
  const int wv = tid >> 6, lane = tid & 63;
  const int row = blockIdx.x, b = row >> 2;
  const int bb = b * Nq, base = row * Nq;

  // ---- hyperparameter MLP (redundant per block, f64 deterministic) ----
  double alpha = (double)alpha_p[0], beta = (double)beta_p[0];
  double iterv = (double)iter_p[0];
  if (tid < Bq) {
    double avg = 0.0;
#pragma unroll
    for (int k = 0; k < Kq; ++k) avg += (double)init_freqs[tid * Kq + k];
    sh_avg[tid] = avg * (1.0 / Kq);
  }
  __syncthreads();
  for (int n = tid; n < 256; n += 128) {
    int b2 = n >> 5, j = n & 31;
    double v = (double)fe_w1[j] * sh_avg[b2] + (double)fe_b1[j];
    sh_h1[b2][j] = v > 0.0 ? v : 0.0;
  }
  __syncthreads();
  {
    int b2 = tid >> 4, j = tid & 15;
    double acc = (double)fe_b2[j];
    for (int i = 0; i < 32; ++i) acc += (double)fe_w2[j * 32 + i] * sh_h1[b2][i];
    sh_z[b2][j] = acc > 0.0 ? acc : 0.0;
  }
  if (tid < Bq) {
    sh_z[tid][16] = alpha;
    sh_z[tid][17] = beta;
  }
  __syncthreads();
  for (int n = tid; n < 512; n += 128) {
    int b2 = n >> 6, j = n & 63;
    double acc = (double)pr_b1[j];
    for (int i = 0; i < 18; ++i) acc += (double)pr_w1[j * 18 + i] * sh_z[b2][i];
    sh_z1[b2][j] = acc > 0.0 ? acc : 0.0;
  }
  __syncthreads();
  for (int n = tid; n < 256; n += 128) {
    int b2 = n >> 5, j = n & 31;
    double acc = (double)pr_b2[j];
    for (int i = 0; i < 64; ++i) acc += (double)pr_w2[j * 64 + i] * sh_z1[b2][i];
    sh_z2[b2][j] = acc > 0.0 ? acc : 0.0;
  }
  __syncthreads();
  if (tid < 16) {
    int b2 = tid >> 1, c = tid & 1;
    double acc = (double)pr_b3[c];
    for (int i = 0; i < 32; ++i) acc += (double)pr_w3[c * 32 + i] * sh_z2[b2][i];
    double fac = 1.0 / (1.0 + exp(-(double)iter_w_p[0] * iterv));
    sh_res[b2][c] = tanh(acc) * fac * 0.1;
  }
  __syncthreads();
  if (tid == 0) {
    double r0 = 0.0, r1 = 0.0;
    for (int q = 0; q < Bq; ++q) { r0 += sh_res[q][0]; r1 += sh_res[q][1]; }
    double na = fmin(fmax(alpha + r0 * alpha * (1.0 / Bq), 1e-6), 0.01);
    double nb = fmin(fmax(beta + r1 * beta * (1.0 / Bq), 1e-6), 0.1);
    double betathr = fmin(pow(10.0, iterv / 36.0 - 10.0), nb);
    sh_hdr[0] = na;
    sh_hdr[1] = 2.0 / na;       // coefA
    sh_hdr[2] = 2.0 / betathr;  // coefS
    sh_hdr[3] = 1.0 / na;       // inv_alpha
    hdr[0] = na;                // for final_kernel (identical across blocks)
    hdr[4] = 1.0 / na;
    out_scal[0] = (float)na;
    out_scal[1] = (float)nb;
  }
  __syncthreads();
  const float coefA = (float)sh_hdr[1];
  const float coefS = (float)sh_hdr[2];
  const double inva = sh_hdr[3];

  // ---- u scale for batch b (per-wave redundant, f64) ----
  double tv[NL];
  {
    const float4* S4 = reinterpret_cast<const float4*>(s + bb);
    const float4* SX4 = reinterpret_cast<const float4*>(sum_x + bb);
    const float4* SY4 = reinterpret_cast<const float4*>(sum_y + bb);
    const float4* L4 = reinterpret_cast<const float4*>(lamuda + bb);
    double n0 = 0.0, n1 = 0.0;
#pragma unroll
    for (int q = 0; q < 8; ++q) {
      float4 av = S4[lane * 8 + q];
      float4 bv = SX4[lane * 8 + q];
      float4 cv = SY4[lane * 8 + q];
      float4 dv = L4[lane * 8 + q];
      int e = 4 * q;
      tv[e + 0] = (double)av.x - (double)bv.x - (double)cv.x - (double)dv.x * inva;
      tv[e + 1] = (double)av.y - (double)bv.y - (double)cv.y - (double)dv.y * inva;
      tv[e + 2] = (double)av.z - (double)bv.z - (double)cv.z - (double)dv.z * inva;
      tv[e + 3] = (double)av.w - (double)bv.w - (double)cv.w - (double)dv.w * inva;
      n0 += tv[e + 0] * tv[e + 0];
      n1 += tv[e + 1] * tv[e + 1];
      n0 += tv[e + 2] * tv[e + 2];
      n1 += tv[e + 3] * tv[e + 3];
    }
    double nsq = wave_sum_d(n0 + n1);
    double nn = sqrt(nsq);
    double ee = sqrt((double)Nq * (double)var_p[0]);
    double scale = (nn > ee) ? ee / fmax(nn, 1e-30) : 1.0;
    if (tid == 0 && (row & 3) == 0) hdr[8 + b] = scale;  // for final_kernel
    double oms = 1.0 - scale;  // resid = tv*(1-scale) + xm*cos + ym*sin
#pragma unroll
    for (int e = 0; e < NL; ++e) tv[e] *= oms;
  }

  // ---- eIF cumtrapz phase + trig + per-wave system build (packed) ----
  const double fsv = (double)fs_p[0];
  const double c0 = PI_D / fsv;
  v2f De[NP], R[NP], X[NP];
  {
    double ev[NL], pl[NL];
    const float4* E4 = reinterpret_cast<const float4*>(eIF + base);
#pragma unroll
    for (int q = 0; q < 8; ++q) {
      float4 e4 = E4[lane * 8 + q];
      ev[4 * q + 0] = (double)e4.x;
      ev[4 * q + 1] = (double)e4.y;
      ev[4 * q + 2] = (double)e4.z;
      ev[4 * q + 3] = (double)e4.w;
    }
    pl[0] = ev[0];
#pragma unroll
    for (int e = 1; e < NL; ++e) pl[e] = pl[e - 1] + ev[e];
    double offs = lane_excl_prefix_d(pl[NL - 1], lane);
    double y0 = __shfl(ev[0], 0, 64);
    const float4* XM4 = reinterpret_cast<const float4*>(xm + base);
    const float4* YM4 = reinterpret_cast<const float4*>(ym + base);
#pragma unroll
    for (int q = 0; q < 8; ++q) {
      float4 xm4 = XM4[lane * 8 + q];
      float4 ym4 = YM4[lane * 8 + q];
      float xa[4] = {xm4.x, xm4.y, xm4.z, xm4.w};
      float ya[4] = {ym4.x, ym4.y, ym4.z, ym4.w};
#pragma unroll
      for (int t2 = 0; t2 < 4; ++t2) {
        int e = 4 * q + t2;
        double ph = c0 * (2.0 * (offs + pl[e]) - ev[e] - y0);  // 2*pi*cumtrapz
        float sn, cs;
        fast_sincos_ph(ph, &sn, &cs);
        float xmv = xa[t2], ymv = ya[t2];
        double resid = tv[e] + (double)xmv * (double)cs + (double)ymv * (double)sn;
        float trig = (wv == 0) ? cs : sn;
        float de = trig * trig + 1e-6f;
        float rr = (float)((double)trig * resid);
        float xx = (wv == 0) ? xmv : ymv;
        int j = e >> 1;
        if (e & 1) {
          De[j].y = de; R[j].y = rr; X[j].y = xx;
        } else {
          De[j].x = de; R[j].x = rr; X[j].x = xx;
        }
      }
    }
  }

  // ---- CG: wave0 solves X system, wave1 solves Y system (parallel) ----
  cg_wave_pk<false, false>(coefA, De, 0.0f, R, X, lane);

  // publish xs/ys
  {
    float* dst = (wv == 0) ? sh_xs : sh_ys;
#pragma unroll
    for (int e = 0; e < NL; ++e) {
      float xv = (e & 1) ? X[e >> 1].y : X[e >> 1].x;
      dst[e * 64 + lane] = xv;
    }
  }
  __syncthreads();

  // ---- deltaIF (both waves identically) ----
  {
    float xs[NL], ys[NL];
#pragma unroll
    for (int e = 0; e < NL; ++e) {
      xs[e] = sh_xs[e * 64 + lane];
      ys[e] = sh_ys[e * 64 + lane];
    }
    float invdx = (float)fsv, inv2dx = 0.5f * invdx;
    float xl = dpp_shr1(xs[NL - 1]), xr = dpp_shl1(xs[0]);
    float yl = dpp_shr1(ys[NL - 1]), yr = dpp_shl1(ys[0]);
#pragma unroll
    for (int e = 0; e < NL; ++e) {
      int i = lane * NL + e;
      float xm1 = (e >= 1) ? xs[e - 1] : xl;
      float xp1 = (e <= NL - 2) ? xs[e + 1] : xr;
      float ym1 = (e >= 1) ? ys[e - 1] : yl;
      float yp1 = (e <= NL - 2) ? ys[e + 1] : yr;
      float xb, yb;
      if (i == 0) {
        xb = (xp1 - xs[e]) * invdx;
        yb = (yp1 - ys[e]) * invdx;
      } else if (i == Nq - 1) {
        xb = (xs[e] - xm1) * invdx;
        yb = (ys[e] - ym1) * invdx;
      } else {
        xb = (xp1 - xm1) * inv2dx;
        yb = (yp1 - ym1) * inv2dx;
      }
      float denom = xs[e] * xs[e] + ys[e] * ys[e] + 1e-12f;
      float rr = (xs[e] * yb - ys[e] * xb) / (denom * (float)TWO_PI_D);
      int j = e >> 1;
      if (e & 1) {
        R[j].y = rr; X[j].y = 0.0f;
      } else {
        R[j].x = rr; X[j].x = 0.0f;
      }
    }
  }

  // ---- smooth CG (both waves redundantly; identical input -> identical) ----
  cg_wave_pk<true, true>(coefS, nullptr, 1.0f + 1e-6f, R, X, lane);

  // ---- epilogue: outputs + new-phase contributions ----
  bool active = mode_mask[row] != 0;
  double eifn[NL], pl[NL];
#pragma unroll
  for (int e = 0; e < NL; ++e) {
    int i = base + lane * NL + e;
    double eifv = (double)eIF[i];
    double sm = (double)((e & 1) ? X[e >> 1].y : X[e >> 1].x);
    eifn[e] = active ? (eifv - 0.5 * sm) : eifv;
  }
  if (wv == 0) {
#pragma unroll
    for (int e = 0; e < NL; ++e) {
      int i = base + lane * NL + e;
      out_eIF[i] = (float)eifn[e];
      out_xm[i] = active ? sh_xs[e * 64 + lane] : xm[i];
    }
  } else {
#pragma unroll
    for (int e = 0; e < NL; ++e) {
      int i = base + lane * NL + e;
      out_ym[i] = active ? sh_ys[e * 64 + lane] : ym[i];
    }
  }
  pl[0] = eifn[0];
#pragma unroll
  for (int e = 1; e < NL; ++e) pl[e] = pl[e - 1] + eifn[e];
  double offs = lane_excl_prefix_d(pl[NL - 1], lane);
  double y0 = __shfl(eifn[0], 0, 64);
#pragma unroll
  for (int e = 0; e < NL; ++e) {
    int i = base + lane * NL + e;
    double ph = c0 * (2.0 * (offs + pl[e]) - eifn[e] - y0);
    float sn, cs;
    fast_sincos_ph(ph, &sn, &cs);
    if (wv == 0)
      cx_w[i] = active ? sh_xs[e * 64 + lane] * cs : 0.0f;
    else
      cy_w[i] = active ? sh_ys[e * 64 + lane] * sn : 0.0f;
  }
}

// ------- final: pure elementwise (scale precomputed by row_kernel) ----------
__global__ __launch_bounds__(128) void final_kernel(
    const float* __restrict__ s, const float* __restrict__ sum_x,
    const float* __restrict__ sum_y, const float* __restrict__ lamuda,
    const double* __restrict__ hdr, const float* __restrict__ cx_w,
    const float* __restrict__ cy_w, float* __restrict__ out_bsx,
    float* __restrict__ out_bsy, float* __restrict__ out_lam) {
  int gi = blockIdx.x * 128 + threadIdx.x;  // 128 blocks x 128 thr = 16384
  int b = gi >> 11, i = gi & (Nq - 1);
  double na = hdr[0], inva = hdr[4], scale = hdr[8 + b];
  double sv = (double)s[gi];
  double t = sv - (double)sum_x[gi] - (double)sum_y[gi] -
             (double)lamuda[gi] * inva;
  double bx = 0.0, by = 0.0;
#pragma unroll
  for (int k = 0; k < Kq; ++k) {  // same f64 ascending-k sum order as before
    bx += (double)cx_w[(b * Kq + k) * Nq + i];
    by += (double)cy_w[(b * Kq + k) * Nq + i];
  }
  double u = t * scale;
  double nl = (double)lamuda[gi] + na * (u + bx + by - sv);
  out_bsx[gi] = (float)bx;
  out_bsy[gi] = (float)by;
  out_lam[gi] = (float)nl;
}

// ---------------- launcher ----------------
extern "C" void kernel_launch(void* const* d_in, const int* in_sizes, int n_in,
                              void* d_out, int out_size, void* d_ws, size_t ws_size,
                              hipStream_t stream) {
  (void)in_sizes; (void)n_in; (void)out_size; (void)ws_size;
  const float* s = (const float*)d_in[0];
  const float* eIF = (const float*)d_in[1];
  const float* xm = (const float*)d_in[2];
  const float* ym = (const float*)d_in[3];
  const float* sum_x = (const float*)d_in[4];
  const float* sum_y = (const float*)d_in[5];
  const float* lamuda = (const float*)d_in[6];
  const float* init_freqs = (const float*)d_in[7];
  const int* mode_mask = (const int*)d_in[8];
  const float* alpha = (const float*)d_in[9];
  const float* beta = (const float*)d_in[10];
  const float* var = (const float*)d_in[11];
  const float* fs = (const float*)d_in[12];
  const int* iteration = (const int*)d_in[13];
  const float* fe_w1 = (const float*)d_in[14];
  const float* fe_b1 = (const float*)d_in[15];
  const float* fe_w2 = (const float*)d_in[16];
  const float* fe_b2 = (const float*)d_in[17];
  const float* pr_w1 = (const float*)d_in[18];
  const float* pr_b1 = (const float*)d_in[19];
  const float* pr_w2 = (const float*)d_in[20];
  const float* pr_b2 = (const float*)d_in[21];
  const float* pr_w3 = (const float*)d_in[22];
  const float* pr_b3 = (const float*)d_in[23];
  const float* iter_weight = (const float*)d_in[24];

  float* out = (float*)d_out;
  const int BN = Bq * Nq;      // 16384
  const int BKN = BKq * Nq;    // 65536
  float* out_eIF = out;
  float* out_xm = out + BKN;
  float* out_ym = out + 2 * BKN;
  float* out_bsx = out + 3 * BKN;
  float* out_bsy = out + 3 * BKN + BN;
  float* out_lam = out + 3 * BKN + 2 * BN;
  float* out_scal = out + 3 * BKN + 3 * BN;  // [new_alpha, new_beta]

  double* W = (double*)d_ws;
  double* hdr = W;                   // 16 doubles: [0]=na [4]=inva [8..15]=scale_b
  float* F = (float*)(W + 16);
  float* cx_w = F;                   // BKN floats
  float* cy_w = F + BKN;             // BKN floats

  row_kernel<<<BKq, 128, 0, stream>>>(
      s, eIF, xm, ym, sum_x, sum_y, lamuda, init_freqs, mode_mask, alpha, beta,
      var, fs, iteration, fe_w1, fe_b1, fe_w2, fe_b2, pr_w1, pr_b1, pr_w2,
      pr_b2, pr_w3, pr_b3, iter_weight, hdr, out_eIF, out_xm, out_ym, cx_w,
      cy_w, out_scal);
  final_kernel<<<BN / 128, 128, 0, stream>>>(s, sum_x, sum_y, lamuda, hdr,
                                             cx_w, cy_w, out_bsx, out_bsy,
                                             out_lam);
}

// Round 7
// 154.565 us; speedup vs baseline: 1.0967x; 1.0725x over previous
//
#include <hip/hip_runtime.h>
#include <math.h>

#define Nq 2048
#define Bq 8
#define Kq 4
#define BKq 32
#define NL 32  // elements per lane (2048 / 64)
#define NP 16  // float2 pairs per lane
#define TWO_PI_D 6.283185307179586
#define PI_D 3.141592653589793
#define INV2PI_D 0.15915494309189535

typedef float v2f __attribute__((ext_vector_type(2)));

__device__ __forceinline__ v2f mk2(float a, float b) {
  v2f r; r.x = a; r.y = b; return r;
}

// ---------------- wave helpers ----------------

__device__ __forceinline__ double wave_sum_d(double v) {
#pragma unroll
  for (int off = 1; off < 64; off <<= 1) v += __shfl_xor(v, off, 64);
  return v;
}

// Canonical GCN DPP wave64 sum (rocPRIM sequence); result broadcast via lane 63.
__device__ __forceinline__ float dpp_sum_f32(float v) {
  v += __int_as_float(__builtin_amdgcn_update_dpp(0, __float_as_int(v), 0x111, 0xf, 0xf, false));  // row_shr:1
  v += __int_as_float(__builtin_amdgcn_update_dpp(0, __float_as_int(v), 0x112, 0xf, 0xf, false));  // row_shr:2
  v += __int_as_float(__builtin_amdgcn_update_dpp(0, __float_as_int(v), 0x114, 0xf, 0xe, false));  // row_shr:4
  v += __int_as_float(__builtin_amdgcn_update_dpp(0, __float_as_int(v), 0x118, 0xf, 0xc, false));  // row_shr:8
  v += __int_as_float(__builtin_amdgcn_update_dpp(0, __float_as_int(v), 0x142, 0xa, 0xf, false));  // row_bcast:15
  v += __int_as_float(__builtin_amdgcn_update_dpp(0, __float_as_int(v), 0x143, 0xc, 0xf, false));  // row_bcast:31
  return __int_as_float(__builtin_amdgcn_readlane(__float_as_int(v), 63));
}

// lane i <- lane i-1 via DPP wave_shr:1; lane0 -> 0 (zero ghost, relied upon)
__device__ __forceinline__ float dpp_shr1(float v) {
  return __int_as_float(__builtin_amdgcn_update_dpp(0, __float_as_int(v), 0x138, 0xf, 0xf, false));
}
// lane i <- lane i+1 via DPP wave_shl:1; lane63 -> 0
__device__ __forceinline__ float dpp_shl1(float v) {
  return __int_as_float(__builtin_amdgcn_update_dpp(0, __float_as_int(v), 0x130, 0xf, 0xf, false));
}

__device__ __forceinline__ double lane_excl_prefix_d(double T, int lane) {
  double acc = T;
#pragma unroll
  for (int off = 1; off < 64; off <<= 1) {
    double t = __shfl_up(acc, off, 64);
    if (lane >= off) acc += t;
  }
  return acc - T;
}

// Input: phase pre-scaled to revolutions (hrev = phase/(2*pi), f64).
// v_sin_f32/v_cos_f32 take REVOLUTIONS natively (D = sin(2*pi*S0)); we reduce
// in f64 (trunc) and feed the fractional revolution directly — removes
// __sincosf's redundant internal range reduction (~10-15 instrs/call).
__device__ __forceinline__ void fast_sincos_rev(double hrev, float* sn, float* cs) {
  double k = trunc(hrev);
  float rv = (float)(hrev - k);  // in (-1, 1): well inside v_sin valid range
  *sn = __builtin_amdgcn_sinf(rv);
  *cs = __builtin_amdgcn_cosf(rv);
}

// ---- packed CG: (coef*opedoub + diag(de)) z = rhs on one wave, f32 state ----
// Round-2 verified form: two DPP reductions per iteration, X/R/rs update pass
// issuing between the trees (hides tree latency), hoisted inv_rsold.
// In: X = x0, R = rhs. Out: X = solution. ZERO_X0 skips the initial matvec.
template <bool UNIT_DIAG, bool ZERO_X0>
__device__ __forceinline__ void cg_wave_pk(float coef, const v2f* De, float deu,
                                           v2f* R, v2f* X, int lane) {
  v2f P[NP], AP[NP];

  // AP = coef * pent(V) + de .* V   (two-step: preserves exact stencil
  // cancellation for near-constant V — critical when coef ~ 1e10).
  // Interior formula everywhere (DPP zero-ghosts at wave edges), then
  // rank-small boundary corrections at lanes 0 / 63.
  // S-trick: S[j] = V[j] + V[j+1] supplies BOTH m1 terms (m1x[j]=S[j-1].y,
  // m1y[j]=S[j].x) — identical operands/order to the scalar form (bitwise
  // equal), 17 pk-adds replacing 32 scalar adds.
  auto applyA = [&](const v2f* V) {
    float lm2 = dpp_shr1(V[NP - 1].x);  // p[-2] (0 at lane 0)
    float lm1 = dpp_shr1(V[NP - 1].y);  // p[-1]
    float rp1 = dpp_shl1(V[0].x);       // p[32] (0 at lane 63)
    float rp2 = dpp_shl1(V[0].y);       // p[33]
    v2f Vm = mk2(lm2, lm1);
    v2f Vp = mk2(rp1, rp2);
    v2f S[NP], Sm;
    Sm = Vm + V[0];                      // Sm.y = p[-1] + p[1] = m1x[0]
#pragma unroll
    for (int j = 0; j < NP - 1; ++j) S[j] = V[j] + V[j + 1];
    S[NP - 1] = V[NP - 1] + Vp;
#pragma unroll
    for (int j = 0; j < NP; ++j) {
      v2f Vprev = (j == 0) ? Vm : V[j - 1];
      v2f Vnext = (j == NP - 1) ? Vp : V[j + 1];
      v2f t = Vprev + Vnext;       // m2 + q2 (pair-aligned)
      t += V[j] * 6.0f;            // + 6 p
      float m1x = (j == 0) ? Sm.y : S[j - 1].y;  // p[2j-1] + p[2j+1]
      float m1y = S[j].x;                         // p[2j]   + p[2j+2]
      t.x -= 4.0f * m1x;
      t.y -= 4.0f * m1y;
      v2f de = UNIT_DIAG ? mk2(deu, deu) : De[j];
      AP[j] = t * coef + de * V[j];
    }
    // Boundary corrections: interior-with-zero-ghosts vs true boundary rows.
    if (lane == 0) {
      AP[0].x += coef * (V[0].y - 4.0f * V[0].x);   // row 0: 2p0-3p1+p2
      AP[0].y += coef * V[0].x;                     // row 1: -3p0+6p1-4p2+p3
    }
    if (lane == 63) {
      AP[NP - 1].x += coef * V[NP - 1].y;                      // row N-2
      AP[NP - 1].y += coef * (V[NP - 1].x - 4.0f * V[NP - 1].y);  // row N-1
    }
  };

  float rsold, inv_rsold;
  {
    if (!ZERO_X0) {
      applyA(X);
#pragma unroll
      for (int j = 0; j < NP; ++j) R[j] -= AP[j];
    }
    v2f a0 = mk2(0.f, 0.f), a1 = mk2(0.f, 0.f);
#pragma unroll
    for (int j = 0; j < NP; j += 2) {
      P[j] = R[j];
      a0 += R[j] * R[j];
      P[j + 1] = R[j + 1];
      a1 += R[j + 1] * R[j + 1];
    }
    v2f s = a0 + a1;
    rsold = dpp_sum_f32(s.x + s.y);
    inv_rsold = __builtin_amdgcn_rcpf(rsold + 1e-12f);  // hidden behind applyA
  }

  for (int it = 0; it < 30; ++it) {
    applyA(P);
    v2f a0 = mk2(0.f, 0.f), a1 = mk2(0.f, 0.f);
#pragma unroll
    for (int j = 0; j < NP; j += 2) {
      a0 += P[j] * AP[j];
      a1 += P[j + 1] * AP[j + 1];
    }
    v2f s = a0 + a1;
    float pap = dpp_sum_f32(s.x + s.y);
    float a = rsold * __builtin_amdgcn_rcpf(pap + 1e-12f);
    v2f r0 = mk2(0.f, 0.f), r1 = mk2(0.f, 0.f);
#pragma unroll
    for (int j = 0; j < NP; j += 2) {
      X[j] += P[j] * a;
      R[j] -= AP[j] * a;
      r0 += R[j] * R[j];
      X[j + 1] += P[j + 1] * a;
      R[j + 1] -= AP[j + 1] * a;
      r1 += R[j + 1] * R[j + 1];
    }
    v2f t = r0 + r1;
    float rsnew = dpp_sum_f32(t.x + t.y);
    if (rsnew < 1e-12f) break;  // == sqrtf(rsnew) < 1e-6f (monotone, nonneg)
    float bta = rsnew * inv_rsold;  // rcp computed one iteration earlier
#pragma unroll
    for (int j = 0; j < NP; ++j) P[j] = R[j] + P[j] * bta;
    rsold = rsnew;
    inv_rsold = __builtin_amdgcn_rcpf(rsnew + 1e-12f);  // hidden behind applyA
  }
}

// ---------- mega kernel: one block per (b,k) row; wave0=X system, wave1=Y ----
__global__ __launch_bounds__(128, 1) void row_kernel(
    const float* __restrict__ s, const float* __restrict__ eIF,
    const float* __restrict__ xm, const float* __restrict__ ym,
    const float* __restrict__ sum_x, const float* __restrict__ sum_y,
    const float* __restrict__ lamuda, const float* __restrict__ init_freqs,
    const int* __restrict__ mode_mask, const float* __restrict__ alpha_p,
    const float* __restrict__ beta_p, const float* __restrict__ var_p,
    const float* __restrict__ fs_p, const int* __restrict__ iter_p,
    const float* __restrict__ fe_w1, const float* __restrict__ fe_b1,
    const float* __restrict__ fe_w2, const float* __restrict__ fe_b2,
    const float* __restrict__ pr_w1, const float* __restrict__ pr_b1,
    const float* __restrict__ pr_w2, const float* __restrict__ pr_b2,
    const float* __restrict__ pr_w3, const float* __restrict__ pr_b3,
    const float* __restrict__ iter_w_p, double* __restrict__ hdr,
    float* __restrict__ out_eIF, float* __restrict__ out_xm,
    float* __restrict__ out_ym, float* __restrict__ cx_w,
    float* __restrict__ cy_w, float* __restrict__ out_scal) {
  __shared__ double sh_avg[Bq];
  __shared__ double sh_h1[Bq][32];
  __shared__ double sh_z[Bq][18];
  __shared__ double sh_z1[Bq][64];
  __shared__ double sh_z2[Bq][32];
  __shared__ double sh_res[Bq][2];
  __shared__ double sh_hdr[6];
  __shared__ float sh_xs[Nq], sh_ys[Nq];

  const int tid = threadIdx.x;
  const int wv = tid >> 6, lane = tid & 63;
  const int row = blockIdx.x, b = row >> 2;
  const int bb = b * Nq, base = row * Nq;

  // ---- hyperparameter MLP (redundant per block, f64 deterministic) ----
  double alpha = (double)alpha_p[0], beta = (double)beta_p[0];
  double iterv = (double)iter_p[0];
  if (tid < Bq) {
    double avg = 0.0;
#pragma unroll
    for (int k = 0; k < Kq; ++k) avg += (double)init_freqs[tid * Kq + k];
    sh_avg[tid] = avg * (1.0 / Kq);
  }
  __syncthreads();
  for (int n = tid; n < 256; n += 128) {
    int b2 = n >> 5, j = n & 31;
    double v = (double)fe_w1[j] * sh_avg[b2] + (double)fe_b1[j];
    sh_h1[b2][j] = v > 0.0 ? v : 0.0;
  }
  __syncthreads();
  {
    int b2 = tid >> 4, j = tid & 15;
    double acc = (double)fe_b2[j];
    for (int i = 0; i < 32; ++i) acc += (double)fe_w2[j * 32 + i] * sh_h1[b2][i];
    sh_z[b2][j] = acc > 0.0 ? acc : 0.0;
  }
  if (tid < Bq) {
    sh_z[tid][16] = alpha;
    sh_z[tid][17] = beta;
  }
  __syncthreads();
  for (int n = tid; n < 512; n += 128) {
    int b2 = n >> 6, j = n & 63;
    double acc = (double)pr_b1[j];
    for (int i = 0; i < 18; ++i) acc += (double)pr_w1[j * 18 + i] * sh_z[b2][i];
    sh_z1[b2][j] = acc > 0.0 ? acc : 0.0;
  }
  __syncthreads();
  for (int n = tid; n < 256; n += 128) {
    int b2 = n >> 5, j = n & 31;
    double acc = (double)pr_b2[j];
    for (int i = 0; i < 64; ++i) acc += (double)pr_w2[j * 64 + i] * sh_z1[b2][i];
    sh_z2[b2][j] = acc > 0.0 ? acc : 0.0;
  }
  __syncthreads();
  if (tid < 16) {
    int b2 = tid >> 1, c = tid & 1;
    double acc = (double)pr_b3[c];
    for (int i = 0; i < 32; ++i) acc += (double)pr_w3[c * 32 + i] * sh_z2[b2][i];
    double fac = 1.0 / (1.0 + exp(-(double)iter_w_p[0] * iterv));
    sh_res[b2][c] = tanh(acc) * fac * 0.1;
  }
  __syncthreads();
  if (tid == 0) {
    double r0 = 0.0, r1 = 0.0;
    for (int q = 0; q < Bq; ++q) { r0 += sh_res[q][0]; r1 += sh_res[q][1]; }
    double na = fmin(fmax(alpha + r0 * alpha * (1.0 / Bq), 1e-6), 0.01);
    double nb = fmin(fmax(beta + r1 * beta * (1.0 / Bq), 1e-6), 0.1);
    double betathr = fmin(pow(10.0, iterv / 36.0 - 10.0), nb);
    sh_hdr[0] = na;
    sh_hdr[1] = 2.0 / na;       // coefA
    sh_hdr[2] = 2.0 / betathr;  // coefS
    sh_hdr[3] = 1.0 / na;       // inv_alpha
    hdr[0] = na;                // for final_kernel (identical across blocks)
    hdr[4] = 1.0 / na;
    out_scal[0] = (float)na;
    out_scal[1] = (float)nb;
  }
  __syncthreads();
  const float coefA = (float)sh_hdr[1];
  const float coefS = (float)sh_hdr[2];
  const double inva = sh_hdr[3];

  // ---- u scale for batch b (per-wave redundant, f64) ----
  double tv[NL];
  {
    const float4* S4 = reinterpret_cast<const float4*>(s + bb);
    const float4* SX4 = reinterpret_cast<const float4*>(sum_x + bb);
    const float4* SY4 = reinterpret_cast<const float4*>(sum_y + bb);
    const float4* L4 = reinterpret_cast<const float4*>(lamuda + bb);
    double n0 = 0.0, n1 = 0.0;
#pragma unroll
    for (int q = 0; q < 8; ++q) {
      float4 av = S4[lane * 8 + q];
      float4 bv = SX4[lane * 8 + q];
      float4 cv = SY4[lane * 8 + q];
      float4 dv = L4[lane * 8 + q];
      int e = 4 * q;
      tv[e + 0] = (double)av.x - (double)bv.x - (double)cv.x - (double)dv.x * inva;
      tv[e + 1] = (double)av.y - (double)bv.y - (double)cv.y - (double)dv.y * inva;
      tv[e + 2] = (double)av.z - (double)bv.z - (double)cv.z - (double)dv.z * inva;
      tv[e + 3] = (double)av.w - (double)bv.w - (double)cv.w - (double)dv.w * inva;
      n0 += tv[e + 0] * tv[e + 0];
      n1 += tv[e + 1] * tv[e + 1];
      n0 += tv[e + 2] * tv[e + 2];
      n1 += tv[e + 3] * tv[e + 3];
    }
    double nsq = wave_sum_d(n0 + n1);
    double nn = sqrt(nsq);
    double ee = sqrt((double)Nq * (double)var_p[0]);
    double scale = (nn > ee) ? ee / fmax(nn, 1e-30) : 1.0;
    if (tid == 0 && (row & 3) == 0) hdr[8 + b] = scale;  // for final_kernel
    double oms = 1.0 - scale;  // resid = tv*(1-scale) + xm*cos + ym*sin
#pragma unroll
    for (int e = 0; e < NL; ++e) tv[e] *= oms;
  }

  // ---- eIF cumtrapz phase + trig + per-wave system build (packed) ----
  const double fsv = (double)fs_p[0];
  const double hdx = 0.5 / fsv;  // (pi*dx)/(2*pi): phase in revolutions
  v2f De[NP], R[NP], X[NP];
  {
    double ev[NL], pl[NL];
    const float4* E4 = reinterpret_cast<const float4*>(eIF + base);
#pragma unroll
    for (int q = 0; q < 8; ++q) {
      float4 e4 = E4[lane * 8 + q];
      ev[4 * q + 0] = (double)e4.x;
      ev[4 * q + 1] = (double)e4.y;
      ev[4 * q + 2] = (double)e4.z;
      ev[4 * q + 3] = (double)e4.w;
    }
    pl[0] = ev[0];
#pragma unroll
    for (int e = 1; e < NL; ++e) pl[e] = pl[e - 1] + ev[e];
    double offs = lane_excl_prefix_d(pl[NL - 1], lane);
    double y0 = __shfl(ev[0], 0, 64);
    const float4* XM4 = reinterpret_cast<const float4*>(xm + base);
    const float4* YM4 = reinterpret_cast<const float4*>(ym + base);
#pragma unroll
    for (int q = 0; q < 8; ++q) {
      float4 xm4 = XM4[lane * 8 + q];
      float4 ym4 = YM4[lane * 8 + q];
      float xa[4] = {xm4.x, xm4.y, xm4.z, xm4.w};
      float ya[4] = {ym4.x, ym4.y, ym4.z, ym4.w};
#pragma unroll
      for (int t2 = 0; t2 < 4; ++t2) {
        int e = 4 * q + t2;
        double hrev = hdx * (2.0 * (offs + pl[e]) - ev[e] - y0);  // cumtrapz rev
        float sn, cs;
        fast_sincos_rev(hrev, &sn, &cs);
        float xmv = xa[t2], ymv = ya[t2];
        double resid = tv[e] + (double)xmv * (double)cs + (double)ymv * (double)sn;
        float trig = (wv == 0) ? cs : sn;
        float de = trig * trig + 1e-6f;
        float rr = (float)((double)trig * resid);
        float xx = (wv == 0) ? xmv : ymv;
        int j = e >> 1;
        if (e & 1) {
          De[j].y = de; R[j].y = rr; X[j].y = xx;
        } else {
          De[j].x = de; R[j].x = rr; X[j].x = xx;
        }
      }
    }
  }

  // ---- CG: wave0 solves X system, wave1 solves Y system (parallel) ----
  cg_wave_pk<false, false>(coefA, De, 0.0f, R, X, lane);

  // publish xs/ys
  {
    float* dst = (wv == 0) ? sh_xs : sh_ys;
#pragma unroll
    for (int e = 0; e < NL; ++e) {
      float xv = (e & 1) ? X[e >> 1].y : X[e >> 1].x;
      dst[e * 64 + lane] = xv;
    }
  }
  __syncthreads();

  // ---- deltaIF (both waves identically) ----
  {
    float xs[NL], ys[NL];
#pragma unroll
    for (int e = 0; e < NL; ++e) {
      xs[e] = sh_xs[e * 64 + lane];
      ys[e] = sh_ys[e * 64 + lane];
    }
    float invdx = (float)fsv, inv2dx = 0.5f * invdx;
    float xl = dpp_shr1(xs[NL - 1]), xr = dpp_shl1(xs[0]);
    float yl = dpp_shr1(ys[NL - 1]), yr = dpp_shl1(ys[0]);
#pragma unroll
    for (int e = 0; e < NL; ++e) {
      int i = lane * NL + e;
      float xm1 = (e >= 1) ? xs[e - 1] : xl;
      float xp1 = (e <= NL - 2) ? xs[e + 1] : xr;
      float ym1 = (e >= 1) ? ys[e - 1] : yl;
      float yp1 = (e <= NL - 2) ? ys[e + 1] : yr;
      float xb, yb;
      if (i == 0) {
        xb = (xp1 - xs[e]) * invdx;
        yb = (yp1 - ys[e]) * invdx;
      } else if (i == Nq - 1) {
        xb = (xs[e] - xm1) * invdx;
        yb = (ys[e] - ym1) * invdx;
      } else {
        xb = (xp1 - xm1) * inv2dx;
        yb = (yp1 - ym1) * inv2dx;
      }
      float denom = xs[e] * xs[e] + ys[e] * ys[e] + 1e-12f;
      float rr = (xs[e] * yb - ys[e] * xb) / (denom * (float)TWO_PI_D);
      int j = e >> 1;
      if (e & 1) {
        R[j].y = rr; X[j].y = 0.0f;
      } else {
        R[j].x = rr; X[j].x = 0.0f;
      }
    }
  }

  // ---- smooth CG (both waves redundantly; identical input -> identical) ----
  cg_wave_pk<true, true>(coefS, nullptr, 1.0f + 1e-6f, R, X, lane);

  // ---- epilogue: outputs + new-phase contributions ----
  bool active = mode_mask[row] != 0;
  double eifn[NL], pl[NL];
#pragma unroll
  for (int e = 0; e < NL; ++e) {
    int i = base + lane * NL + e;
    double eifv = (double)eIF[i];
    double sm = (double)((e & 1) ? X[e >> 1].y : X[e >> 1].x);
    eifn[e] = active ? (eifv - 0.5 * sm) : eifv;
  }
  if (wv == 0) {
#pragma unroll
    for (int e = 0; e < NL; ++e) {
      int i = base + lane * NL + e;
      out_eIF[i] = (float)eifn[e];
      out_xm[i] = active ? sh_xs[e * 64 + lane] : xm[i];
    }
  } else {
#pragma unroll
    for (int e = 0; e < NL; ++e) {
      int i = base + lane * NL + e;
      out_ym[i] = active ? sh_ys[e * 64 + lane] : ym[i];
    }
  }
  pl[0] = eifn[0];
#pragma unroll
  for (int e = 1; e < NL; ++e) pl[e] = pl[e - 1] + eifn[e];
  double offs = lane_excl_prefix_d(pl[NL - 1], lane);
  double y0 = __shfl(eifn[0], 0, 64);
#pragma unroll
  for (int e = 0; e < NL; ++e) {
    int i = base + lane * NL + e;
    double hrev = hdx * (2.0 * (offs + pl[e]) - eifn[e] - y0);
    float sn, cs;
    fast_sincos_rev(hrev, &sn, &cs);
    if (wv == 0)
      cx_w[i] = active ? sh_xs[e * 64 + lane] * cs : 0.0f;
    else
      cy_w[i] = active ? sh_ys[e * 64 + lane] * sn : 0.0f;
  }
}

// ------- final: pure elementwise (scale precomputed by row_kernel) ----------
__global__ __launch_bounds__(128) void final_kernel(
    const float* __restrict__ s, const float* __restrict__ sum_x,
    const float* __restrict__ sum_y, const float* __restrict__ lamuda,
    const double* __restrict__ hdr, const float* __restrict__ cx_w,
    const float* __restrict__ cy_w, float* __restrict__ out_bsx,
    float* __restrict__ out_bsy, float* __restrict__ out_lam) {
  int gi = blockIdx.x * 128 + threadIdx.x;  // 128 blocks x 128 thr = 16384
  int b = gi >> 11, i = gi & (Nq - 1);
  double na = hdr[0], inva = hdr[4], scale = hdr[8 + b];
  double sv = (double)s[gi];
  double t = sv - (double)sum_x[gi] - (double)sum_y[gi] -
             (double)lamuda[gi] * inva;
  double bx = 0.0, by = 0.0;
#pragma unroll
  for (int k = 0; k < Kq; ++k) {  // same f64 ascending-k sum order as before
    bx += (double)cx_w[(b * Kq + k) * Nq + i];
    by += (double)cy_w[(b * Kq + k) * Nq + i];
  }
  double u = t * scale;
  double nl = (double)lamuda[gi] + na * (u + bx + by - sv);
  out_bsx[gi] = (float)bx;
  out_bsy[gi] = (float)by;
  out_lam[gi] = (float)nl;
}

// ---------------- launcher ----------------
extern "C" void kernel_launch(void* const* d_in, const int* in_sizes, int n_in,
                              void* d_out, int out_size, void* d_ws, size_t ws_size,
                              hipStream_t stream) {
  (void)in_sizes; (void)n_in; (void)out_size; (void)ws_size;
  const float* s = (const float*)d_in[0];
  const float* eIF = (const float*)d_in[1];
  const float* xm = (const float*)d_in[2];
  const float* ym = (const float*)d_in[3];
  const float* sum_x = (const float*)d_in[4];
  const float* sum_y = (const float*)d_in[5];
  const float* lamuda = (const float*)d_in[6];
  const float* init_freqs = (const float*)d_in[7];
  const int* mode_mask = (const int*)d_in[8];
  const float* alpha = (const float*)d_in[9];
  const float* beta = (const float*)d_in[10];
  const float* var = (const float*)d_in[11];
  const float* fs = (const float*)d_in[12];
  const int* iteration = (const int*)d_in[13];
  const float* fe_w1 = (const float*)d_in[14];
  const float* fe_b1 = (const float*)d_in[15];
  const float* fe_w2 = (const float*)d_in[16];
  const float* fe_b2 = (const float*)d_in[17];
  const float* pr_w1 = (const float*)d_in[18];
  const float* pr_b1 = (const float*)d_in[19];
  const float* pr_w2 = (const float*)d_in[20];
  const float* pr_b2 = (const float*)d_in[21];
  const float* pr_w3 = (const float*)d_in[22];
  const float* pr_b3 = (const float*)d_in[23];
  const float* iter_weight = (const float*)d_in[24];

  float* out = (float*)d_out;
  const int BN = Bq * Nq;      // 16384
  const int BKN = BKq * Nq;    // 65536
  float* out_eIF = out;
  float* out_xm = out + BKN;
  float* out_ym = out + 2 * BKN;
  float* out_bsx = out + 3 * BKN;
  float* out_bsy = out + 3 * BKN + BN;
  float* out_lam = out + 3 * BKN + 2 * BN;
  float* out_scal = out + 3 * BKN + 3 * BN;  // [new_alpha, new_beta]

  double* W = (double*)d_ws;
  double* hdr = W;                   // 16 doubles: [0]=na [4]=inva [8..15]=scale_b
  float* F = (float*)(W + 16);
  float* cx_w = F;                   // BKN floats
  float* cy_w = F + BKN;             // BKN floats

  row_kernel<<<BKq, 128, 0, stream>>>(
      s, eIF, xm, ym, sum_x, sum_y, lamuda, init_freqs, mode_mask, alpha, beta,
      var, fs, iteration, fe_w1, fe_b1, fe_w2, fe_b2, pr_w1, pr_b1, pr_w2,
      pr_b2, pr_w3, pr_b3, iter_weight, hdr, out_eIF, out_xm, out_ym, cx_w,
      cy_w, out_scal);
  final_kernel<<<BN / 128, 128, 0, stream>>>(s, sum_x, sum_y, lamuda, hdr,
                                             cx_w, cy_w, out_bsx, out_bsy,
                                             out_lam);
}